// Round 8
// baseline (1080.284 us; speedup 1.0000x reference)
//
#include <hip/hip_runtime.h>

#define HD 128  // hidden/feature dim (fixed by problem)

typedef _Float16 f16x8 __attribute__((ext_vector_type(8)));
typedef _Float16 f16x2 __attribute__((ext_vector_type(2)));
typedef float f32x4 __attribute__((ext_vector_type(4)));

// ---------------- GEMM block role: C = op(A @ W + b) (*scale[row]) ----------------
// block = 256 (4 waves) = 128 rows; wave = 32 rows x 128 cols (2 m-tiles).
// WF16: W pre-converted f16 fragment-order (32 KB vector copy, conflict-free).
// else: W fp32 k-major, converted in-kernel (enc1 only; conflicts hidden under D1's
// atomic-bound phase).
template<bool RELU, bool SCALE, bool CVT, bool WF16>
__device__ __forceinline__ void gemm_block(
    _Float16* lds, int bi,
    const _Float16* __restrict__ Ab, const float* __restrict__ Af0,
    const float* __restrict__ Af1, const void* __restrict__ Wsrc,
    const float* __restrict__ bias, const float* __restrict__ scale,
    _Float16* __restrict__ C, int N, int Ntot) {
  const int tid = threadIdx.x;
  if (WF16) {
    const _Float16* Wf = (const _Float16*)Wsrc;
    #pragma unroll
    for (int i = 0; i < 8; ++i)   // 16 B/lane contiguous: conflict-free b128
      *(float4*)&lds[tid * 8 + i * 2048] = *(const float4*)&Wf[tid * 8 + i * 2048];
  } else {
    const float* Wg = (const float*)Wsrc;
    #pragma unroll
    for (int i = 0; i < 16; ++i) {
      int flat = i * 1024 + tid * 4;
      int k = flat >> 7, n0 = flat & 127;
      float4 w4 = *(const float4*)(Wg + flat);
      int kc = k >> 5, q = (k >> 3) & 3, j = k & 7;
      float wv[4] = {w4.x, w4.y, w4.z, w4.w};
      #pragma unroll
      for (int d = 0; d < 4; ++d) {
        int n = n0 + d;
        lds[(size_t)(((n >> 4) * 4 + kc) * 64 + 16 * q + (n & 15)) * 8 + j] = (_Float16)wv[d];
      }
    }
  }
  __syncthreads();

  const int lane = tid & 63;
  const int wave = tid >> 6;
  const int n16 = lane & 15, q = lane >> 4;
  const int rowbase = bi * 128 + wave * 32;

  int arow[2];
  #pragma unroll
  for (int t = 0; t < 2; ++t) {
    int r = rowbase + 16 * t + n16;
    arow[t] = (r < Ntot) ? r : (Ntot - 1);
  }

  f32x4 acc[2][8];
  #pragma unroll
  for (int t = 0; t < 2; ++t)
    #pragma unroll
    for (int nt = 0; nt < 8; ++nt) acc[t][nt] = (f32x4){0.f, 0.f, 0.f, 0.f};

  #pragma unroll
  for (int kc = 0; kc < 4; ++kc) {
    f16x8 a[2];
    #pragma unroll
    for (int t = 0; t < 2; ++t) {
      if (CVT) {
        int r = arow[t];
        const float* src = (r < N) ? (Af0 + (size_t)r * HD) : (Af1 + (size_t)(r - N) * HD);
        float4 u0 = *(const float4*)(src + kc * 32 + q * 8);
        float4 u1 = *(const float4*)(src + kc * 32 + q * 8 + 4);
        union { _Float16 h[8]; f16x8 v; } tmp;
        tmp.h[0] = (_Float16)u0.x; tmp.h[1] = (_Float16)u0.y;
        tmp.h[2] = (_Float16)u0.z; tmp.h[3] = (_Float16)u0.w;
        tmp.h[4] = (_Float16)u1.x; tmp.h[5] = (_Float16)u1.y;
        tmp.h[6] = (_Float16)u1.z; tmp.h[7] = (_Float16)u1.w;
        a[t] = tmp.v;
      } else {
        a[t] = *(const f16x8*)(Ab + (size_t)arow[t] * HD + kc * 32 + q * 8);
      }
    }
    #pragma unroll
    for (int nt = 0; nt < 8; ++nt) {
      f16x8 b = *(const f16x8*)&lds[(size_t)((nt * 4 + kc) * 64 + lane) * 8];
      #pragma unroll
      for (int t = 0; t < 2; ++t)
        acc[t][nt] = __builtin_amdgcn_mfma_f32_16x16x32_f16(a[t], b, acc[t][nt], 0, 0, 0);
    }
  }

  float bv[8];
  #pragma unroll
  for (int nt = 0; nt < 8; ++nt) bv[nt] = bias[nt * 16 + n16];

  #pragma unroll
  for (int t = 0; t < 2; ++t) {
    #pragma unroll
    for (int r = 0; r < 4; ++r) {
      int row = rowbase + 16 * t + 4 * q + r;
      if (row < Ntot) {
        float s = SCALE ? scale[row] : 1.0f;
        #pragma unroll
        for (int nt = 0; nt < 8; ++nt) {
          float v = acc[t][nt][r] + bv[nt];
          if (RELU) v = fmaxf(v, 0.f);
          if (SCALE) v *= s;
          C[(size_t)row * HD + nt * 16 + n16] = (_Float16)v;
        }
      }
    }
  }
}

// ---------------- fused GEMM + aux roles, role-interleaved over blockIdx ----------
// AUX 1: deg_slot (2*degB aux blocks) then W1..3 frag-f16 convert (24 blocks).
// AUX 2: per-block exclusive deg-scan + dis; LAST block also scans partials.
// AUX 4: CSR fill (atomic-free, lazy offs).
// PAT 0: [aux,aux,gemm] (needs A>=2G). PAT 1: [gemm,gemm,aux] (needs G>=2A).
// PAT 2: all gemm.
template<bool RELU, bool SCALE, bool CVT, bool WF16, int AUX, int PAT>
__global__ __launch_bounds__(256, 4) void k_fused(
    const _Float16* __restrict__ Ab, const float* __restrict__ Af0,
    const float* __restrict__ Af1, const void* __restrict__ Wsrc,
    const float* __restrict__ bias, const float* __restrict__ scale,
    _Float16* __restrict__ C, int N, int Ntot, int G, int A,
    const int* __restrict__ ei0, const int* __restrict__ ei1, int E,
    int* __restrict__ deg2, unsigned short* __restrict__ slot,
    const float* __restrict__ w1, const float* __restrict__ w2,
    const float* __restrict__ w3, _Float16* __restrict__ WfOut, int degB,
    int* __restrict__ offs, int* __restrict__ partials,
    float* __restrict__ dis, int scanB,
    unsigned short* __restrict__ csr_col, int fillB, int* __restrict__ ctr) {
  __shared__ _Float16 lds[16384];  // 32 KB (GEMM W tile / scan scratch)
  __shared__ int lastFlag;
  const int bi = blockIdx.x;
  const int t = threadIdx.x;

  int role, rid;  // role 0 = gemm, 1 = aux
  if (PAT == 2) { role = 0; rid = bi; }
  else if (PAT == 0) {
    if (bi < 3 * G) { int k = bi / 3, r = bi % 3;
      if (r == 2) { role = 0; rid = k; } else { role = 1; rid = 2 * k + r; } }
    else { role = 1; rid = bi - G; }
  } else {
    if (bi < 3 * A) { int k = bi / 3, r = bi % 3;
      if (r == 2) { role = 1; rid = k; } else { role = 0; rid = 2 * k + r; } }
    else { role = 0; rid = bi - A; }
  }

  if (role == 0) {
    gemm_block<RELU, SCALE, CVT, WF16>(lds, rid, Ab, Af0, Af1, Wsrc,
                                       bias, scale, C, N, Ntot);
    return;
  }

  if (AUX == 1) {
    if (rid < 2 * degB) {   // degree + slot for graph g (4 edges/thread)
      int g = (rid >= degB);
      int cb = rid - g * degB;
      const int* rows = g ? ei1 : ei0;
      int* deg = deg2 + g * N;
      unsigned short* sl = slot + (size_t)g * E;
      int base = (cb * 256 + t) * 4;
      if (base + 3 < E) {
        int4 r = *(const int4*)(rows + base);
        union { unsigned short us[4]; uint2 v; } s;
        s.us[0] = (unsigned short)atomicAdd(&deg[r.x], 1);
        s.us[1] = (unsigned short)atomicAdd(&deg[r.y], 1);
        s.us[2] = (unsigned short)atomicAdd(&deg[r.z], 1);
        s.us[3] = (unsigned short)atomicAdd(&deg[r.w], 1);
        *(uint2*)(sl + base) = s.v;
      } else {
        for (int e = base; e < E; ++e)
          sl[e] = (unsigned short)atomicAdd(&deg[rows[e]], 1);
      }
    } else {               // W1..W3 fp32 -> f16 fragment-order (8 elems/thread)
      int wb = rid - 2 * degB;         // 0..23
      int m = wb >> 3;                 // 0..2
      const float* Wg = (m == 0) ? w1 : (m == 1) ? w2 : w3;
      int idx0 = (wb & 7) * 2048 + t * 8;
      float4 u0 = *(const float4*)(Wg + idx0);
      float4 u1 = *(const float4*)(Wg + idx0 + 4);
      int k = idx0 >> 7, n0 = idx0 & 127;
      int kc = k >> 5, q2 = (k >> 3) & 3, j = k & 7;
      _Float16* dst = WfOut + (size_t)m * 16384;
      float vv[8] = {u0.x, u0.y, u0.z, u0.w, u1.x, u1.y, u1.z, u1.w};
      #pragma unroll
      for (int d = 0; d < 8; ++d) {
        int n = n0 + d;
        dst[(size_t)(((n >> 4) * 4 + kc) * 64 + 16 * q2 + (n & 15)) * 8 + j] = (_Float16)vv[d];
      }
    }
  } else if (AUX == 2) {   // per-block exclusive scan + dis; last block: pscan
    int* s = (int*)lds;
    int i = rid * 256 + t;
    int v = (i < Ntot) ? deg2[i] : 0;
    s[t] = v;
    __syncthreads();
    #pragma unroll
    for (int off = 1; off < 256; off <<= 1) {
      int x = (t >= off) ? s[t - off] : 0;
      __syncthreads();
      s[t] += x;
      __syncthreads();
    }
    if (i < Ntot) {
      offs[i] = s[t] - v;
      dis[i] = (v > 0) ? (1.0f / sqrtf((float)v)) : 0.0f;
    }
    if (t == 255) partials[rid] = s[255];
    __syncthreads();
    if (t == 0) {
      __threadfence();
      lastFlag = (atomicAdd(ctr, 1) == scanB - 1);
    }
    __syncthreads();
    if (lastFlag) {        // exclusive scan of partials[0..scanB), scanB <= 512
      __threadfence();
      volatile int* vp = partials;
      int P = scanB;
      int v0 = (t < P) ? vp[t] : 0;
      int v1 = (t + 256 < P) ? vp[t + 256] : 0;
      __syncthreads();
      s[t] = v0;
      s[t + 256] = v1;
      __syncthreads();
      #pragma unroll
      for (int off = 1; off < 256; off <<= 1) {
        int x0 = (t >= off) ? s[t - off] : 0;
        int x1 = (t >= off) ? s[256 + t - off] : 0;
        __syncthreads();
        s[t] += x0;
        s[256 + t] += x1;
        __syncthreads();
      }
      int tot0 = s[255];
      if (t < P) partials[t] = s[t] - v0;
      if (t + 256 < P) partials[t + 256] = s[256 + t] + tot0 - v1;
    }
  } else if (AUX == 4) {   // CSR fill: no atomics; off = offs[n] + partials[n>>8]
    int g = (rid >= fillB);
    int cb = rid - g * fillB;
    const int* eg = (g ? ei1 : ei0);
    const int* ob = offs + g * N;
    const unsigned short* sl = slot + (size_t)g * E;
    int gN = g * N;
    int base = (cb * 256 + t) * 4;
    if (base + 3 < E) {
      int4 r = *(const int4*)(eg + base);
      int4 c = *(const int4*)(eg + E + base);
      uint2 sv = *(const uint2*)(sl + base);
      csr_col[ob[r.x] + partials[(gN + r.x) >> 8] + (sv.x & 0xffff)] = (unsigned short)c.x;
      csr_col[ob[r.y] + partials[(gN + r.y) >> 8] + (sv.x >> 16)]    = (unsigned short)c.y;
      csr_col[ob[r.z] + partials[(gN + r.z) >> 8] + (sv.y & 0xffff)] = (unsigned short)c.z;
      csr_col[ob[r.w] + partials[(gN + r.w) >> 8] + (sv.y >> 16)]    = (unsigned short)c.w;
    } else {
      for (int e = base; e < E; ++e)
        csr_col[ob[eg[e]] + partials[(gN + eg[e]) >> 8] + sl[e]] = (unsigned short)eg[E + e];
    }
  }
}

// ---------------- CSR aggregate: out[r] = relu(dis[r]*sum T[col]) ----------------
// one wave/node; 16 lanes/row (uint4 = 8 f16/lane); packed-f16 accumulate.
// POOL: skip row write, reduce into replica pools; LAST block runs the final MLP.
template<bool POOL>
__global__ __launch_bounds__(256) void k_aggregate(
    const _Float16* __restrict__ T, const int* __restrict__ offs,
    const int* __restrict__ partials, const unsigned short* __restrict__ csr_col,
    const float* __restrict__ dis, _Float16* __restrict__ out,
    float* __restrict__ poolrep, int N, int Ntot, int Etot,
    const float* __restrict__ W1, const float* __restrict__ b1,
    const float* __restrict__ W2, const float* __restrict__ b2,
    float* __restrict__ result, float invN, int* __restrict__ ctr, int nBlocks) {
  __shared__ float red[4][128];
  __shared__ int lastFlag;
  const int lane = threadIdx.x & 63;
  const int wave = threadIdx.x >> 6;
  const int gw = blockIdx.x * 4 + wave;
  const int sub = lane >> 4, c16 = lane & 15;

  f16x2 hacc[4];
  #pragma unroll
  for (int j = 0; j < 4; ++j) hacc[j] = (f16x2){(_Float16)0.f, (_Float16)0.f};

  if (gw < Ntot) {
    const int beg = offs[gw] + partials[gw >> 8];
    const int end = (gw + 1 == Ntot) ? Etot : (offs[gw + 1] + partials[(gw + 1) >> 8]);
    const uint4* Tg = (const uint4*)(T + (size_t)(gw >= N ? N : 0) * HD);
    for (int e = beg; e < end; e += 16) {
      uint4 v[4];
      #pragma unroll
      for (int gp = 0; gp < 4; ++gp) {
        v[gp] = make_uint4(0, 0, 0, 0);
        if (e + 4 * gp < end) {              // wave-uniform
          int eg = e + 4 * gp + sub;
          bool valid = (eg < end);
          int ce = valid ? eg : (end - 1);
          int col = csr_col[ce];
          uint4 tv = Tg[(size_t)col * 16 + c16];
          if (valid) v[gp] = tv;
        }
      }
      #pragma unroll
      for (int gp = 0; gp < 4; ++gp) {
        union { uint4 u; f16x2 h[4]; } w;
        w.u = v[gp];
        hacc[0] += w.h[0];
        hacc[1] += w.h[1];
        hacc[2] += w.h[2];
        hacc[3] += w.h[3];
      }
    }
  }

  float ax[8];
  #pragma unroll
  for (int j = 0; j < 4; ++j) {
    ax[2 * j]     = (float)hacc[j][0];
    ax[2 * j + 1] = (float)hacc[j][1];
  }
  #pragma unroll
  for (int j = 0; j < 8; ++j) {
    ax[j] += __shfl_xor(ax[j], 32, 64);
    ax[j] += __shfl_xor(ax[j], 16, 64);
  }
  float dr = (gw < Ntot) ? dis[gw] : 0.f;
  #pragma unroll
  for (int j = 0; j < 8; ++j) ax[j] = fmaxf(ax[j] * dr, 0.f);

  if (!POOL) {
    if (gw < Ntot && sub == 0) {
      union { uint4 u; _Float16 h[8]; } o;
      #pragma unroll
      for (int j = 0; j < 8; ++j) o.h[j] = (_Float16)ax[j];
      ((uint4*)out)[(size_t)gw * 16 + c16] = o.u;
    }
    return;
  }

  // POOL: block-reduce into replica pools
  if (sub == 0) {
    *(float4*)&red[wave][c16 * 8]     = make_float4(ax[0], ax[1], ax[2], ax[3]);
    *(float4*)&red[wave][c16 * 8 + 4] = make_float4(ax[4], ax[5], ax[6], ax[7]);
  }
  __syncthreads();
  int t = threadIdx.x;
  if (t < 128) {
    float s = red[0][t] + red[1][t] + red[2][t] + red[3][t];
    int g = (blockIdx.x * 4 >= N) ? 1 : 0;
    atomicAdd(&poolrep[(size_t)((blockIdx.x & 15) * 2 + g) * 128 + t], s);
  }
  __syncthreads();
  if (t == 0) {
    __threadfence();
    lastFlag = (atomicAdd(ctr, 1) == nBlocks - 1);
  }
  __syncthreads();
  if (!lastFlag) return;

  // last block: final similarity MLP (128 threads = waves 0,1)
  __threadfence();
  __shared__ float cs[512];
  __shared__ float red2[2];
  float g1 = 0.f, g2 = 0.f;
  if (t < 128) {
    #pragma unroll
    for (int r = 0; r < 16; ++r) {
      g1 += *(volatile float*)&poolrep[r * 256 + t];
      g2 += *(volatile float*)&poolrep[r * 256 + 128 + t];
    }
    g1 *= invN;
    g2 *= invN;
    cs[t] = g1;
    cs[128 + t] = g2;
    cs[256 + t] = fabsf(g1 - g2);
    cs[384 + t] = g1 * g2;
  }
  __syncthreads();
  if (t < 128) {
    float acc = b1[t];
    #pragma unroll 8
    for (int i = 0; i < 512; ++i) acc = fmaf(cs[i], W1[(size_t)i * HD + t], acc);
    float h = fmaxf(acc, 0.f);
    float v = h * W2[t];
    #pragma unroll
    for (int off = 32; off > 0; off >>= 1) v += __shfl_down(v, off, 64);
    if ((t & 63) == 0) red2[t >> 6] = v;
  }
  __syncthreads();
  if (t == 0) result[0] = red2[0] + red2[1] + b2[0];
}

extern "C" void kernel_launch(void* const* d_in, const int* in_sizes, int n_in,
                              void* d_out, int out_size, void* d_ws, size_t ws_size,
                              hipStream_t stream) {
  const float* x1     = (const float*)d_in[0];
  const int*   ei1    = (const int*)d_in[1];
  const float* x2     = (const float*)d_in[2];
  const int*   ei2    = (const int*)d_in[3];
  const float* W_in[4] = {(const float*)d_in[4], (const float*)d_in[6],
                          (const float*)d_in[8], (const float*)d_in[10]};
  const float* B_in[4] = {(const float*)d_in[5], (const float*)d_in[7],
                          (const float*)d_in[9], (const float*)d_in[11]};
  const float* sim_w1 = (const float*)d_in[12];
  const float* sim_b1 = (const float*)d_in[13];
  const float* sim_w2 = (const float*)d_in[14];
  const float* sim_b2 = (const float*)d_in[15];

  const int N = in_sizes[0] / HD;
  const int E = in_sizes[1] / 2;
  const int Ntot = 2 * N;

  // workspace layout (16B-aligned chunks first)
  _Float16* sp = (_Float16*)d_ws;
  _Float16* bufA = sp; sp += (size_t)Ntot * HD;
  _Float16* bufB = sp; sp += (size_t)Ntot * HD;
  _Float16* WfB  = sp; sp += 3 * 16384;           // enc2, conv1, conv2 frag-order f16
  float* fp = (float*)sp;
  float* dis     = fp; fp += Ntot;
  float* poolrep = fp; fp += 16 * 256;            // zeroed with ctrs+deg2 (adjacent)
  int* ip = (int*)fp;
  int* ctrs     = ip; ip += 8;                    // [0]=pscan ctr, [1]=final ctr
  int* deg2     = ip; ip += Ntot;
  int* offs     = ip; ip += Ntot;
  int* partials = ip; ip += 512;
  ip = (int*)(((uintptr_t)ip + 15) & ~(uintptr_t)15);
  unsigned short* slot = (unsigned short*)ip;       // 2E ushorts
  unsigned short* csr_col = slot + 2 * (size_t)E;   // 2E ushorts

  const int G = (Ntot + 127) / 128;                 // 782 gemm blocks
  const int scanB = (Ntot + 255) / 256;             // 391 (<=512 required)
  const int aggB  = (Ntot + 3) / 4;                 // 25000
  const int degB  = ((E + 3) / 4 + 255) / 256;      // 782 per graph
  const int fillB = degB;

  // one memset: poolrep + ctrs + deg2 (adjacent)
  hipMemsetAsync(poolrep, 0, (16 * 256 + 8 + Ntot) * sizeof(float), stream);

  // D1: deg_slot + W1..3 convert (aux, A = 2*degB+24) interleaved with enc1 (G)
  {
    int A = 2 * degB + 24;                          // 1588 >= 2G = 1564
    k_fused<true, false, true, false, 1, 0><<<A + G, 256, 0, stream>>>(
        nullptr, x1, x2, W_in[0], B_in[0], nullptr, bufA, N, Ntot, G, A,
        ei1, ei2, E, deg2, slot, W_in[1], W_in[2], W_in[3], WfB, degB,
        offs, partials, dis, scanB, csr_col, fillB, ctrs);
  }
  // D2: scan+dis (aux, A = scanB; last block pscans) interleaved with enc2 (G = 2A)
  k_fused<false, false, false, true, 2, 1><<<scanB + G, 256, 0, stream>>>(
      bufA, nullptr, nullptr, WfB + 0 * 16384, B_in[1], nullptr, bufB, N, Ntot, G, scanB,
      ei1, ei2, E, deg2, slot, nullptr, nullptr, nullptr, nullptr, degB,
      offs, partials, dis, scanB, csr_col, fillB, ctrs);
  // D3: CSR fill (aux, A = 2*fillB = 2G) interleaved with conv1 (T=(h@W+b)*dis)
  k_fused<false, true, false, true, 4, 0><<<2 * fillB + G, 256, 0, stream>>>(
      bufB, nullptr, nullptr, WfB + 1 * 16384, B_in[2], dis, bufA, N, Ntot, G, 2 * fillB,
      ei1, ei2, E, deg2, slot, nullptr, nullptr, nullptr, nullptr, degB,
      offs, partials, dis, scanB, csr_col, fillB, ctrs);
  // D4: aggregate 1
  k_aggregate<false><<<aggB, 256, 0, stream>>>(
      bufA, offs, partials, csr_col, dis, bufB, nullptr, N, Ntot, 2 * E,
      nullptr, nullptr, nullptr, nullptr, nullptr, 0.f, nullptr, 0);
  // D5: conv2 GEMM
  k_fused<false, true, false, true, 0, 2><<<G, 256, 0, stream>>>(
      bufB, nullptr, nullptr, WfB + 2 * 16384, B_in[3], dis, bufA, N, Ntot, G, 0,
      ei1, ei2, E, deg2, slot, nullptr, nullptr, nullptr, nullptr, degB,
      offs, partials, dis, scanB, csr_col, fillB, ctrs);
  // D6: aggregate 2 + pool + (last block) final MLP
  k_aggregate<true><<<aggB, 256, 0, stream>>>(
      bufA, offs, partials, csr_col, dis, nullptr, poolrep, N, Ntot, 2 * E,
      sim_w1, sim_b1, sim_w2, sim_b2, (float*)d_out, 1.0f / (float)N, ctrs + 1, aggB);
}

// Round 9
// 409.323 us; speedup vs baseline: 2.6392x; 2.6392x over previous
//
#include <hip/hip_runtime.h>

#define HD 128  // hidden/feature dim (fixed by problem)

typedef _Float16 f16x8 __attribute__((ext_vector_type(8)));
typedef _Float16 f16x2 __attribute__((ext_vector_type(2)));
typedef float f32x4 __attribute__((ext_vector_type(4)));

// ---------------- GEMM block role: C = op(A @ W + b) (*scale[row]) ----------------
// block = 256 (4 waves) = 128 rows; wave = 32 rows x 128 cols (2 m-tiles).
// WF16: W pre-converted f16 fragment-order (32 KB vector copy, conflict-free).
// else: W fp32 k-major, converted in-kernel (enc1 only; conflicts hidden under D1's
// atomic-bound phase).
template<bool RELU, bool SCALE, bool CVT, bool WF16>
__device__ __forceinline__ void gemm_block(
    _Float16* lds, int bi,
    const _Float16* __restrict__ Ab, const float* __restrict__ Af0,
    const float* __restrict__ Af1, const void* __restrict__ Wsrc,
    const float* __restrict__ bias, const float* __restrict__ scale,
    _Float16* __restrict__ C, int N, int Ntot) {
  const int tid = threadIdx.x;
  if (WF16) {
    const _Float16* Wf = (const _Float16*)Wsrc;
    #pragma unroll
    for (int i = 0; i < 8; ++i)   // 16 B/lane contiguous: conflict-free b128
      *(float4*)&lds[tid * 8 + i * 2048] = *(const float4*)&Wf[tid * 8 + i * 2048];
  } else {
    const float* Wg = (const float*)Wsrc;
    #pragma unroll
    for (int i = 0; i < 16; ++i) {
      int flat = i * 1024 + tid * 4;
      int k = flat >> 7, n0 = flat & 127;
      float4 w4 = *(const float4*)(Wg + flat);
      int kc = k >> 5, q = (k >> 3) & 3, j = k & 7;
      float wv[4] = {w4.x, w4.y, w4.z, w4.w};
      #pragma unroll
      for (int d = 0; d < 4; ++d) {
        int n = n0 + d;
        lds[(size_t)(((n >> 4) * 4 + kc) * 64 + 16 * q + (n & 15)) * 8 + j] = (_Float16)wv[d];
      }
    }
  }
  __syncthreads();

  const int lane = tid & 63;
  const int wave = tid >> 6;
  const int n16 = lane & 15, q = lane >> 4;
  const int rowbase = bi * 128 + wave * 32;

  int arow[2];
  #pragma unroll
  for (int t = 0; t < 2; ++t) {
    int r = rowbase + 16 * t + n16;
    arow[t] = (r < Ntot) ? r : (Ntot - 1);
  }

  f32x4 acc[2][8];
  #pragma unroll
  for (int t = 0; t < 2; ++t)
    #pragma unroll
    for (int nt = 0; nt < 8; ++nt) acc[t][nt] = (f32x4){0.f, 0.f, 0.f, 0.f};

  #pragma unroll
  for (int kc = 0; kc < 4; ++kc) {
    f16x8 a[2];
    #pragma unroll
    for (int t = 0; t < 2; ++t) {
      if (CVT) {
        int r = arow[t];
        const float* src = (r < N) ? (Af0 + (size_t)r * HD) : (Af1 + (size_t)(r - N) * HD);
        float4 u0 = *(const float4*)(src + kc * 32 + q * 8);
        float4 u1 = *(const float4*)(src + kc * 32 + q * 8 + 4);
        union { _Float16 h[8]; f16x8 v; } tmp;
        tmp.h[0] = (_Float16)u0.x; tmp.h[1] = (_Float16)u0.y;
        tmp.h[2] = (_Float16)u0.z; tmp.h[3] = (_Float16)u0.w;
        tmp.h[4] = (_Float16)u1.x; tmp.h[5] = (_Float16)u1.y;
        tmp.h[6] = (_Float16)u1.z; tmp.h[7] = (_Float16)u1.w;
        a[t] = tmp.v;
      } else {
        a[t] = *(const f16x8*)(Ab + (size_t)arow[t] * HD + kc * 32 + q * 8);
      }
    }
    #pragma unroll
    for (int nt = 0; nt < 8; ++nt) {
      f16x8 b = *(const f16x8*)&lds[(size_t)((nt * 4 + kc) * 64 + lane) * 8];
      #pragma unroll
      for (int t = 0; t < 2; ++t)
        acc[t][nt] = __builtin_amdgcn_mfma_f32_16x16x32_f16(a[t], b, acc[t][nt], 0, 0, 0);
    }
  }

  float bv[8];
  #pragma unroll
  for (int nt = 0; nt < 8; ++nt) bv[nt] = bias[nt * 16 + n16];

  #pragma unroll
  for (int t = 0; t < 2; ++t) {
    #pragma unroll
    for (int r = 0; r < 4; ++r) {
      int row = rowbase + 16 * t + 4 * q + r;
      if (row < Ntot) {
        float s = SCALE ? scale[row] : 1.0f;
        #pragma unroll
        for (int nt = 0; nt < 8; ++nt) {
          float v = acc[t][nt][r] + bv[nt];
          if (RELU) v = fmaxf(v, 0.f);
          if (SCALE) v *= s;
          C[(size_t)row * HD + nt * 16 + n16] = (_Float16)v;
        }
      }
    }
  }
}

// ---------------- fused GEMM + aux roles, role-interleaved over blockIdx ----------
// AUX 1: deg_slot (2*degB aux blocks) then W1..3 frag-f16 convert (24 blocks).
// AUX 2: per-block exclusive deg-scan + dis; LAST block also scans partials
//        (391 fences total — measured tolerable; do NOT do this at 25k-block scale).
// AUX 4: CSR fill (atomic-free, lazy offs).
// PAT 0: [aux,aux,gemm] (needs A>=2G). PAT 1: [gemm,gemm,aux] (needs G>=2A).
// PAT 2: all gemm.
template<bool RELU, bool SCALE, bool CVT, bool WF16, int AUX, int PAT>
__global__ __launch_bounds__(256, 4) void k_fused(
    const _Float16* __restrict__ Ab, const float* __restrict__ Af0,
    const float* __restrict__ Af1, const void* __restrict__ Wsrc,
    const float* __restrict__ bias, const float* __restrict__ scale,
    _Float16* __restrict__ C, int N, int Ntot, int G, int A,
    const int* __restrict__ ei0, const int* __restrict__ ei1, int E,
    int* __restrict__ deg2, unsigned short* __restrict__ slot,
    const float* __restrict__ w1, const float* __restrict__ w2,
    const float* __restrict__ w3, _Float16* __restrict__ WfOut, int degB,
    int* __restrict__ offs, int* __restrict__ partials,
    float* __restrict__ dis, int scanB,
    unsigned short* __restrict__ csr_col, int fillB, int* __restrict__ ctr) {
  __shared__ _Float16 lds[16384];  // 32 KB (GEMM W tile / scan scratch)
  __shared__ int lastFlag;
  const int bi = blockIdx.x;
  const int t = threadIdx.x;

  int role, rid;  // role 0 = gemm, 1 = aux
  if (PAT == 2) { role = 0; rid = bi; }
  else if (PAT == 0) {
    if (bi < 3 * G) { int k = bi / 3, r = bi % 3;
      if (r == 2) { role = 0; rid = k; } else { role = 1; rid = 2 * k + r; } }
    else { role = 1; rid = bi - G; }
  } else {
    if (bi < 3 * A) { int k = bi / 3, r = bi % 3;
      if (r == 2) { role = 1; rid = k; } else { role = 0; rid = 2 * k + r; } }
    else { role = 0; rid = bi - A; }
  }

  if (role == 0) {
    gemm_block<RELU, SCALE, CVT, WF16>(lds, rid, Ab, Af0, Af1, Wsrc,
                                       bias, scale, C, N, Ntot);
    return;
  }

  if (AUX == 1) {
    if (rid < 2 * degB) {   // degree + slot for graph g (4 edges/thread)
      int g = (rid >= degB);
      int cb = rid - g * degB;
      const int* rows = g ? ei1 : ei0;
      int* deg = deg2 + g * N;
      unsigned short* sl = slot + (size_t)g * E;
      int base = (cb * 256 + t) * 4;
      if (base + 3 < E) {
        int4 r = *(const int4*)(rows + base);
        union { unsigned short us[4]; uint2 v; } s;
        s.us[0] = (unsigned short)atomicAdd(&deg[r.x], 1);
        s.us[1] = (unsigned short)atomicAdd(&deg[r.y], 1);
        s.us[2] = (unsigned short)atomicAdd(&deg[r.z], 1);
        s.us[3] = (unsigned short)atomicAdd(&deg[r.w], 1);
        *(uint2*)(sl + base) = s.v;
      } else {
        for (int e = base; e < E; ++e)
          sl[e] = (unsigned short)atomicAdd(&deg[rows[e]], 1);
      }
    } else {               // W1..W3 fp32 -> f16 fragment-order (8 elems/thread)
      int wb = rid - 2 * degB;         // 0..23
      int m = wb >> 3;                 // 0..2
      const float* Wg = (m == 0) ? w1 : (m == 1) ? w2 : w3;
      int idx0 = (wb & 7) * 2048 + t * 8;
      float4 u0 = *(const float4*)(Wg + idx0);
      float4 u1 = *(const float4*)(Wg + idx0 + 4);
      int k = idx0 >> 7, n0 = idx0 & 127;
      int kc = k >> 5, q2 = (k >> 3) & 3, j = k & 7;
      _Float16* dst = WfOut + (size_t)m * 16384;
      float vv[8] = {u0.x, u0.y, u0.z, u0.w, u1.x, u1.y, u1.z, u1.w};
      #pragma unroll
      for (int d = 0; d < 8; ++d) {
        int n = n0 + d;
        dst[(size_t)(((n >> 4) * 4 + kc) * 64 + 16 * q2 + (n & 15)) * 8 + j] = (_Float16)vv[d];
      }
    }
  } else if (AUX == 2) {   // per-block exclusive scan + dis; last block: pscan
    int* s = (int*)lds;
    int i = rid * 256 + t;
    int v = (i < Ntot) ? deg2[i] : 0;
    s[t] = v;
    __syncthreads();
    #pragma unroll
    for (int off = 1; off < 256; off <<= 1) {
      int x = (t >= off) ? s[t - off] : 0;
      __syncthreads();
      s[t] += x;
      __syncthreads();
    }
    if (i < Ntot) {
      offs[i] = s[t] - v;
      dis[i] = (v > 0) ? (1.0f / sqrtf((float)v)) : 0.0f;
    }
    if (t == 255) partials[rid] = s[255];
    __syncthreads();
    if (t == 0) {
      __threadfence();
      lastFlag = (atomicAdd(ctr, 1) == scanB - 1);
    }
    __syncthreads();
    if (lastFlag) {        // exclusive scan of partials[0..scanB), scanB <= 512
      __threadfence();
      volatile int* vp = partials;
      int P = scanB;
      int v0 = (t < P) ? vp[t] : 0;
      int v1 = (t + 256 < P) ? vp[t + 256] : 0;
      __syncthreads();
      s[t] = v0;
      s[t + 256] = v1;
      __syncthreads();
      #pragma unroll
      for (int off = 1; off < 256; off <<= 1) {
        int x0 = (t >= off) ? s[t - off] : 0;
        int x1 = (t >= off) ? s[256 + t - off] : 0;
        __syncthreads();
        s[t] += x0;
        s[256 + t] += x1;
        __syncthreads();
      }
      int tot0 = s[255];
      if (t < P) partials[t] = s[t] - v0;
      if (t + 256 < P) partials[t + 256] = s[256 + t] + tot0 - v1;
    }
  } else if (AUX == 4) {   // CSR fill: no atomics; off = offs[n] + partials[n>>8]
    int g = (rid >= fillB);
    int cb = rid - g * fillB;
    const int* eg = (g ? ei1 : ei0);
    const int* ob = offs + g * N;
    const unsigned short* sl = slot + (size_t)g * E;
    int gN = g * N;
    int base = (cb * 256 + t) * 4;
    if (base + 3 < E) {
      int4 r = *(const int4*)(eg + base);
      int4 c = *(const int4*)(eg + E + base);
      uint2 sv = *(const uint2*)(sl + base);
      csr_col[ob[r.x] + partials[(gN + r.x) >> 8] + (sv.x & 0xffff)] = (unsigned short)c.x;
      csr_col[ob[r.y] + partials[(gN + r.y) >> 8] + (sv.x >> 16)]    = (unsigned short)c.y;
      csr_col[ob[r.z] + partials[(gN + r.z) >> 8] + (sv.y & 0xffff)] = (unsigned short)c.z;
      csr_col[ob[r.w] + partials[(gN + r.w) >> 8] + (sv.y >> 16)]    = (unsigned short)c.w;
    } else {
      for (int e = base; e < E; ++e)
        csr_col[ob[eg[e]] + partials[(gN + eg[e]) >> 8] + sl[e]] = (unsigned short)eg[E + e];
    }
  }
}

// ---------------- CSR aggregate: out[r] = relu(dis[r]*sum T[col]) ----------------
// one wave/node; 16 lanes/row (uint4 = 8 f16/lane); packed-f16 accumulate.
// POOL: skip row write, reduce into replica pools. NO device fences here —
// a per-block __threadfence at 25k-block scale serialized the TCC (round 8:
// 785 us, VALUBusy 4%). Final MLP is a separate tiny dispatch.
template<bool POOL>
__global__ __launch_bounds__(256) void k_aggregate(
    const _Float16* __restrict__ T, const int* __restrict__ offs,
    const int* __restrict__ partials, const unsigned short* __restrict__ csr_col,
    const float* __restrict__ dis, _Float16* __restrict__ out,
    float* __restrict__ poolrep, int N, int Ntot, int Etot) {
  __shared__ float red[4][128];
  const int lane = threadIdx.x & 63;
  const int wave = threadIdx.x >> 6;
  const int gw = blockIdx.x * 4 + wave;
  const int sub = lane >> 4, c16 = lane & 15;

  f16x2 hacc[4];
  #pragma unroll
  for (int j = 0; j < 4; ++j) hacc[j] = (f16x2){(_Float16)0.f, (_Float16)0.f};

  if (gw < Ntot) {
    const int beg = offs[gw] + partials[gw >> 8];
    const int end = (gw + 1 == Ntot) ? Etot : (offs[gw + 1] + partials[(gw + 1) >> 8]);
    const uint4* Tg = (const uint4*)(T + (size_t)(gw >= N ? N : 0) * HD);
    for (int e = beg; e < end; e += 16) {
      uint4 v[4];
      #pragma unroll
      for (int gp = 0; gp < 4; ++gp) {
        v[gp] = make_uint4(0, 0, 0, 0);
        if (e + 4 * gp < end) {              // wave-uniform
          int eg = e + 4 * gp + sub;
          bool valid = (eg < end);
          int ce = valid ? eg : (end - 1);
          int col = csr_col[ce];
          uint4 tv = Tg[(size_t)col * 16 + c16];
          if (valid) v[gp] = tv;
        }
      }
      #pragma unroll
      for (int gp = 0; gp < 4; ++gp) {
        union { uint4 u; f16x2 h[4]; } w;
        w.u = v[gp];
        hacc[0] += w.h[0];
        hacc[1] += w.h[1];
        hacc[2] += w.h[2];
        hacc[3] += w.h[3];
      }
    }
  }

  float ax[8];
  #pragma unroll
  for (int j = 0; j < 4; ++j) {
    ax[2 * j]     = (float)hacc[j][0];
    ax[2 * j + 1] = (float)hacc[j][1];
  }
  #pragma unroll
  for (int j = 0; j < 8; ++j) {
    ax[j] += __shfl_xor(ax[j], 32, 64);
    ax[j] += __shfl_xor(ax[j], 16, 64);
  }
  float dr = (gw < Ntot) ? dis[gw] : 0.f;
  #pragma unroll
  for (int j = 0; j < 8; ++j) ax[j] = fmaxf(ax[j] * dr, 0.f);

  if (!POOL) {
    if (gw < Ntot && sub == 0) {
      union { uint4 u; _Float16 h[8]; } o;
      #pragma unroll
      for (int j = 0; j < 8; ++j) o.h[j] = (_Float16)ax[j];
      ((uint4*)out)[(size_t)gw * 16 + c16] = o.u;
    }
  } else {
    if (sub == 0) {
      *(float4*)&red[wave][c16 * 8]     = make_float4(ax[0], ax[1], ax[2], ax[3]);
      *(float4*)&red[wave][c16 * 8 + 4] = make_float4(ax[4], ax[5], ax[6], ax[7]);
    }
    __syncthreads();
    int t = threadIdx.x;
    if (t < 128) {
      float s = red[0][t] + red[1][t] + red[2][t] + red[3][t];
      int g = (blockIdx.x * 4 >= N) ? 1 : 0;
      atomicAdd(&poolrep[(size_t)((blockIdx.x & 15) * 2 + g) * 128 + t], s);
    }
  }
}

// ---------------- final similarity MLP (tiny, fp32) ----------------
__global__ void k_final(const float* __restrict__ poolrep,
                        const float* __restrict__ W1, const float* __restrict__ b1,
                        const float* __restrict__ W2, const float* __restrict__ b2,
                        float* __restrict__ out, float invN) {
  __shared__ float cs[512];
  __shared__ float red[2];
  int t = threadIdx.x;  // 128 threads
  float g1 = 0.f, g2 = 0.f;
  #pragma unroll
  for (int r = 0; r < 16; ++r) {
    g1 += poolrep[r * 256 + t];
    g2 += poolrep[r * 256 + 128 + t];
  }
  g1 *= invN;
  g2 *= invN;
  cs[t] = g1;
  cs[128 + t] = g2;
  cs[256 + t] = fabsf(g1 - g2);
  cs[384 + t] = g1 * g2;
  __syncthreads();
  float acc = b1[t];
  #pragma unroll 8
  for (int i = 0; i < 512; ++i) acc = fmaf(cs[i], W1[(size_t)i * HD + t], acc);
  float h = fmaxf(acc, 0.f);
  float v = h * W2[t];
  #pragma unroll
  for (int off = 32; off > 0; off >>= 1) v += __shfl_down(v, off, 64);
  if ((t & 63) == 0) red[t >> 6] = v;
  __syncthreads();
  if (t == 0) out[0] = red[0] + red[1] + b2[0];
}

extern "C" void kernel_launch(void* const* d_in, const int* in_sizes, int n_in,
                              void* d_out, int out_size, void* d_ws, size_t ws_size,
                              hipStream_t stream) {
  const float* x1     = (const float*)d_in[0];
  const int*   ei1    = (const int*)d_in[1];
  const float* x2     = (const float*)d_in[2];
  const int*   ei2    = (const int*)d_in[3];
  const float* W_in[4] = {(const float*)d_in[4], (const float*)d_in[6],
                          (const float*)d_in[8], (const float*)d_in[10]};
  const float* B_in[4] = {(const float*)d_in[5], (const float*)d_in[7],
                          (const float*)d_in[9], (const float*)d_in[11]};
  const float* sim_w1 = (const float*)d_in[12];
  const float* sim_b1 = (const float*)d_in[13];
  const float* sim_w2 = (const float*)d_in[14];
  const float* sim_b2 = (const float*)d_in[15];

  const int N = in_sizes[0] / HD;
  const int E = in_sizes[1] / 2;
  const int Ntot = 2 * N;

  // workspace layout (16B-aligned chunks first)
  _Float16* sp = (_Float16*)d_ws;
  _Float16* bufA = sp; sp += (size_t)Ntot * HD;
  _Float16* bufB = sp; sp += (size_t)Ntot * HD;
  _Float16* WfB  = sp; sp += 3 * 16384;           // enc2, conv1, conv2 frag-order f16
  float* fp = (float*)sp;
  float* dis     = fp; fp += Ntot;
  float* poolrep = fp; fp += 16 * 256;            // zeroed with ctrs+deg2 (adjacent)
  int* ip = (int*)fp;
  int* ctrs     = ip; ip += 8;                    // [0]=pscan ctr
  int* deg2     = ip; ip += Ntot;
  int* offs     = ip; ip += Ntot;
  int* partials = ip; ip += 512;
  ip = (int*)(((uintptr_t)ip + 15) & ~(uintptr_t)15);
  unsigned short* slot = (unsigned short*)ip;       // 2E ushorts
  unsigned short* csr_col = slot + 2 * (size_t)E;   // 2E ushorts

  const int G = (Ntot + 127) / 128;                 // 782 gemm blocks
  const int scanB = (Ntot + 255) / 256;             // 391 (<=512 required)
  const int aggB  = (Ntot + 3) / 4;                 // 25000
  const int degB  = ((E + 3) / 4 + 255) / 256;      // 782 per graph
  const int fillB = degB;

  // one memset: poolrep + ctrs + deg2 (adjacent)
  hipMemsetAsync(poolrep, 0, (16 * 256 + 8 + Ntot) * sizeof(float), stream);

  // D1: deg_slot + W1..3 convert (aux, A = 2*degB+24) interleaved with enc1 (G)
  {
    int A = 2 * degB + 24;                          // 1588 >= 2G = 1564
    k_fused<true, false, true, false, 1, 0><<<A + G, 256, 0, stream>>>(
        nullptr, x1, x2, W_in[0], B_in[0], nullptr, bufA, N, Ntot, G, A,
        ei1, ei2, E, deg2, slot, W_in[1], W_in[2], W_in[3], WfB, degB,
        offs, partials, dis, scanB, csr_col, fillB, ctrs);
  }
  // D2: scan+dis (aux, A = scanB; last block pscans) interleaved with enc2 (G = 2A)
  k_fused<false, false, false, true, 2, 1><<<scanB + G, 256, 0, stream>>>(
      bufA, nullptr, nullptr, WfB + 0 * 16384, B_in[1], nullptr, bufB, N, Ntot, G, scanB,
      ei1, ei2, E, deg2, slot, nullptr, nullptr, nullptr, nullptr, degB,
      offs, partials, dis, scanB, csr_col, fillB, ctrs);
  // D3: CSR fill (aux, A = 2*fillB = 2G) interleaved with conv1 (T=(h@W+b)*dis)
  k_fused<false, true, false, true, 4, 0><<<2 * fillB + G, 256, 0, stream>>>(
      bufB, nullptr, nullptr, WfB + 1 * 16384, B_in[2], dis, bufA, N, Ntot, G, 2 * fillB,
      ei1, ei2, E, deg2, slot, nullptr, nullptr, nullptr, nullptr, degB,
      offs, partials, dis, scanB, csr_col, fillB, ctrs);
  // D4: aggregate 1
  k_aggregate<false><<<aggB, 256, 0, stream>>>(
      bufA, offs, partials, csr_col, dis, bufB, nullptr, N, Ntot, 2 * E);
  // D5: conv2 GEMM
  k_fused<false, true, false, true, 0, 2><<<G, 256, 0, stream>>>(
      bufB, nullptr, nullptr, WfB + 2 * 16384, B_in[3], dis, bufA, N, Ntot, G, 0,
      ei1, ei2, E, deg2, slot, nullptr, nullptr, nullptr, nullptr, degB,
      offs, partials, dis, scanB, csr_col, fillB, ctrs);
  // D6: aggregate 2 + pool (replica atomics only — no fences)
  k_aggregate<true><<<aggB, 256, 0, stream>>>(
      bufA, offs, partials, csr_col, dis, nullptr, poolrep, N, Ntot, 2 * E);
  // D7: final MLP
  k_final<<<1, 128, 0, stream>>>(poolrep, sim_w1, sim_b1, sim_w2, sim_b2,
                                 (float*)d_out, 1.0f / (float)N);
}